// Round 5
// baseline (1478.138 us; speedup 1.0000x reference)
//
#include <hip/hip_runtime.h>
#include <hip/hip_cooperative_groups.h>
#include <stdint.h>

namespace cg = cooperative_groups;

typedef __attribute__((ext_vector_type(8))) short s8_t;    // 8 x bf16 (as short bits)
typedef __attribute__((ext_vector_type(4))) short s4v_t;   // 4 x bf16
typedef __attribute__((ext_vector_type(4))) float f4_t;    // MFMA accumulator
typedef unsigned short u16;

#define V_  50000
#define E_  300
#define EP_ 320
#define H_  512
#define G_  1536
#define O_  64
#define T_  21
#define B_  256
#define S_  128
#define BS_ 32768

__device__ __forceinline__ float b2f(u16 u) {
    union { unsigned int u; float f; } v; v.u = ((unsigned int)u) << 16; return v.f;
}
__device__ __forceinline__ u16 f2b(float f) {
    union { float f; unsigned int u; } v; v.f = f;
    unsigned int r = v.u + 0x7fffu + ((v.u >> 16) & 1u);
    return (u16)(r >> 16);
}
__device__ __forceinline__ float fsig(float x) {
    return __builtin_amdgcn_rcpf(1.f + __expf(-x));
}
__device__ __forceinline__ float ftanh(float x) {
    return 1.f - 2.f * __builtin_amdgcn_rcpf(1.f + __expf(2.f * x));
}

// ---------------- weight prep: fp32 -> bf16 (hi/lo split for W_hh) ----------------
__global__ void prep_kernel(const float* wih_f, const float* wih_b,
                            const float* whh_f, const float* whh_b,
                            const float* ner_w,
                            u16* wih_bf, u16* whh_hi, u16* whh_lo, u16* nerw_bf)
{
    const int NW = 3072 * EP_;
    const int NH = 2 * G_ * H_;
    const int NN = 32 * 1024;
    int stride = gridDim.x * blockDim.x;
    for (int i = blockIdx.x * blockDim.x + threadIdx.x; i < NW + NH + NN; i += stride) {
        if (i < NW) {
            int n = i / EP_, k = i % EP_;
            float v = 0.f;
            if (k < E_) v = (n < G_) ? wih_f[n * E_ + k] : wih_b[(n - G_) * E_ + k];
            wih_bf[i] = f2b(v);
        } else if (i < NW + NH) {
            int j = i - NW;
            int d = j / (G_ * H_), r = j % (G_ * H_);
            float v = d == 0 ? whh_f[r] : whh_b[r];
            u16 hi = f2b(v);
            whh_hi[j] = hi;
            whh_lo[j] = f2b(v - b2f(hi));
        } else {
            int j = i - NW - NH;
            int t = j / 1024, k = j % 1024;
            nerw_bf[j] = f2b(t < T_ ? ner_w[t * 1024 + k] : 0.f);
        }
    }
}

// ---------------- embedding gather -> xe bf16 [s*B+b][EP_] (K padded w/ zeros) ----
__global__ void gather_kernel(const int* x, const float* emb, u16* xe)
{
    int stride = gridDim.x * blockDim.x;
    for (int i = blockIdx.x * blockDim.x + threadIdx.x; i < BS_ * EP_; i += stride) {
        int m = i / EP_, k = i % EP_;
        int s = m >> 8, b = m & 255;
        float v = 0.f;
        if (k < E_) v = emb[(size_t)x[b * S_ + s] * E_ + k];
        xe[i] = f2b(v);
    }
}

// ---------------- persistent BiGRU, XCD-local groups ------------------------------
// 256 blocks, 1/CU (LDS-forced), 2 waves x 32 rows (B re-read 8x not 16x -> half LDS
// traffic). Flag barrier: leader stores flag[g][hs]; wave0 lanes 0-31 poll all 32
// flags with one coalesced load. x-GEMM(t+1) overlaps the wait. buffer_inv = L1-only
// invalidate (group shares one XCD L2). Fallback if placement != 32/XCD: grid.sync.
#define WST 520   // u16 stride for whh LDS rows
#define XST 328   // u16 stride for wih LDS rows
__global__ __launch_bounds__(128, 1) void gru_persist(
    const u16* __restrict__ xe, const u16* __restrict__ wih,
    const float* bih_f, const float* bih_b,
    const u16* __restrict__ whh_hi, const u16* __restrict__ whh_lo,
    const float* bhh_f, const float* bhh_b,
    u16* h_hi, u16* h_lo_pp, unsigned int* flag, unsigned int* xcnt)
{
    __shared__ u16 sWhi[48 * WST];
    __shared__ u16 sWlo[48 * WST];
    __shared__ u16 sWx [48 * XST];
    __shared__ unsigned int role_sh[2];

    cg::grid_group grid = cg::this_grid();
    int tid = threadIdx.x, l = tid & 63, wid = tid >> 6;   // wid 0..1

    if (tid == 0) {
        unsigned int xcc = __builtin_amdgcn_s_getreg((7u << 11) | 20u) & 7u;
        unsigned int slot = __hip_atomic_fetch_add(&xcnt[xcc], 1u,
                                __ATOMIC_RELAXED, __HIP_MEMORY_SCOPE_AGENT);
        role_sh[0] = xcc; role_sh[1] = slot;
    }
    grid.sync();
    bool fast = true;
    for (int i = 0; i < 8; ++i)
        fast = fast && (__hip_atomic_load(&xcnt[i], __ATOMIC_RELAXED,
                            __HIP_MEMORY_SCOPE_AGENT) == 32u);
    int g, hs;
    if (fast) { g = (int)role_sh[0]; hs = (int)role_sh[1]; }
    else      { g = blockIdx.x >> 5; hs = blockIdx.x & 31; }
    int dir = g >> 2, bt = g & 3;
    int r0  = bt * 64 + wid * 32;        // wave covers rows r0..r0+31 (2 tiles)
    int hc0 = hs * 16;

    // ---- stage W slice into LDS (once) ----
    for (int idx = tid; idx < 48 * 64; idx += 128) {
        int rr = idx >> 6, ck = (idx & 63) * 8;
        int gcol = (rr >> 4) * H_ + hc0 + (rr & 15);
        size_t goff = ((size_t)dir * G_ + gcol) * (size_t)H_ + ck;
        *(s8_t*)&sWhi[rr * WST + ck] = *(const s8_t*)&whh_hi[goff];
        *(s8_t*)&sWlo[rr * WST + ck] = *(const s8_t*)&whh_lo[goff];
    }
    for (int idx = tid; idx < 48 * 40; idx += 128) {
        int rr = idx / 40, ck = (idx % 40) * 8;
        int gcol = (rr >> 4) * H_ + hc0 + (rr & 15);
        size_t goff = ((size_t)dir * G_ + gcol) * (size_t)EP_ + ck;
        *(s8_t*)&sWx[rr * XST + ck] = *(const s8_t*)&wih[goff];
    }
    __syncthreads();

    int lr = l & 15, lk = (l >> 4) * 8;
    int lc = l & 15, lr4 = (l >> 4) * 4;
    int hc = hc0 + lc;
    const float* bih = dir ? bih_b : bih_f;
    const float* bhh = dir ? bhh_b : bhh_f;
    float br  = bih[hc] + bhh[hc];
    float bz  = bih[H_ + hc] + bhh[H_ + hc];
    float bxn = bih[2 * H_ + hc];
    float bhn = bhh[2 * H_ + hc];
    float hstate[2][4] = {};

    f4_t xac[3][2];                       // r, z, xn accumulators (x-part first)
    auto xgemm = [&](int ttx) {
#pragma unroll
        for (int c = 0; c < 3; ++c)
#pragma unroll
            for (int rt = 0; rt < 2; ++rt) xac[c][rt] = (f4_t){0.f, 0.f, 0.f, 0.f};
        const u16* xp0 = xe + ((size_t)ttx * B_ + r0 + lr) * EP_ + lk;
        const u16* xp1 = xp0 + (size_t)16 * EP_;
#pragma unroll
        for (int kk = 0; kk < 10; ++kk) {
            s8_t ax0 = *(const s8_t*)(xp0 + kk * 32);
            s8_t ax1 = *(const s8_t*)(xp1 + kk * 32);
#pragma unroll
            for (int c = 0; c < 3; ++c) {
                s8_t bx = *(const s8_t*)&sWx[(c * 16 + lr) * XST + lk + kk * 32];
                xac[c][0] = __builtin_amdgcn_mfma_f32_16x16x32_bf16(ax0, bx, xac[c][0], 0, 0, 0);
                xac[c][1] = __builtin_amdgcn_mfma_f32_16x16x32_bf16(ax1, bx, xac[c][1], 0, 0, 0);
            }
        }
    };

    xgemm(dir ? (S_ - 1) : 0);            // prologue: x-part for t=0

#pragma unroll 1
    for (int t = 0; t < S_; ++t) {
        int tt = dir ? (S_ - 1 - t) : t;

        if (t > 0) {
            unsigned int tgt = (unsigned int)t;
            if (fast) {
                if (tid < 64) {
                    int slot = l & 31;
                    while (__hip_atomic_load(&flag[g * 32 + slot], __ATOMIC_RELAXED,
                                             __HIP_MEMORY_SCOPE_AGENT) < tgt)
                        __builtin_amdgcn_s_sleep(1);
                }
                __syncthreads();
                asm volatile("buffer_inv" ::: "memory");
            } else {
                __threadfence();
                grid.sync();
                __threadfence();
            }
        }

        f4_t ahn[2] = {{0.f,0.f,0.f,0.f}, {0.f,0.f,0.f,0.f}};
        if (t > 0) {
            int prev = dir ? (tt + 1) : (tt - 1);
            const u16* hb_hi = h_hi + ((size_t)dir * S_ + prev) * B_ * H_ + (size_t)(r0 + lr) * H_ + lk;
            const u16* hb_lo = h_lo_pp + ((size_t)(((t - 1) & 1) * 2) + dir) * B_ * H_ + (size_t)(r0 + lr) * H_ + lk;
#pragma unroll
            for (int kk = 0; kk < 16; ++kk) {
                s8_t ah0 = *(const s8_t*)(hb_hi + kk * 32);
                s8_t al0 = *(const s8_t*)(hb_lo + kk * 32);
                s8_t ah1 = *(const s8_t*)(hb_hi + (size_t)16 * H_ + kk * 32);
                s8_t al1 = *(const s8_t*)(hb_lo + (size_t)16 * H_ + kk * 32);
#pragma unroll
                for (int c = 0; c < 3; ++c) {
                    s8_t bh = *(const s8_t*)&sWhi[(c * 16 + lr) * WST + lk + kk * 32];
                    s8_t bl = *(const s8_t*)&sWlo[(c * 16 + lr) * WST + lk + kk * 32];
                    if (c < 2) {
                        xac[c][0] = __builtin_amdgcn_mfma_f32_16x16x32_bf16(ah0, bh, xac[c][0], 0, 0, 0);
                        xac[c][0] = __builtin_amdgcn_mfma_f32_16x16x32_bf16(ah0, bl, xac[c][0], 0, 0, 0);
                        xac[c][0] = __builtin_amdgcn_mfma_f32_16x16x32_bf16(al0, bh, xac[c][0], 0, 0, 0);
                        xac[c][1] = __builtin_amdgcn_mfma_f32_16x16x32_bf16(ah1, bh, xac[c][1], 0, 0, 0);
                        xac[c][1] = __builtin_amdgcn_mfma_f32_16x16x32_bf16(ah1, bl, xac[c][1], 0, 0, 0);
                        xac[c][1] = __builtin_amdgcn_mfma_f32_16x16x32_bf16(al1, bh, xac[c][1], 0, 0, 0);
                    } else {
                        ahn[0] = __builtin_amdgcn_mfma_f32_16x16x32_bf16(ah0, bh, ahn[0], 0, 0, 0);
                        ahn[0] = __builtin_amdgcn_mfma_f32_16x16x32_bf16(ah0, bl, ahn[0], 0, 0, 0);
                        ahn[0] = __builtin_amdgcn_mfma_f32_16x16x32_bf16(al0, bh, ahn[0], 0, 0, 0);
                        ahn[1] = __builtin_amdgcn_mfma_f32_16x16x32_bf16(ah1, bh, ahn[1], 0, 0, 0);
                        ahn[1] = __builtin_amdgcn_mfma_f32_16x16x32_bf16(ah1, bl, ahn[1], 0, 0, 0);
                        ahn[1] = __builtin_amdgcn_mfma_f32_16x16x32_bf16(al1, bh, ahn[1], 0, 0, 0);
                    }
                }
            }
        }

        u16* hw_hi = h_hi + ((size_t)dir * S_ + tt) * B_ * H_;
        u16* hw_lo = h_lo_pp + ((size_t)((t & 1) * 2) + dir) * B_ * H_;
#pragma unroll
        for (int rt = 0; rt < 2; ++rt) {
#pragma unroll
            for (int r = 0; r < 4; ++r) {
                int row = r0 + rt * 16 + lr4 + r;
                float pre_r = xac[0][rt][r] + br;
                float pre_z = xac[1][rt][r] + bz;
                float xn = xac[2][rt][r] + bxn;
                float hnv = ahn[rt][r] + bhn;
                float rg = fsig(pre_r);
                float zg = fsig(pre_z);
                float ng = ftanh(xn + rg * hnv);
                float hnew = (1.f - zg) * ng + zg * hstate[rt][r];
                hstate[rt][r] = hnew;
                u16 hib = f2b(hnew);
                hw_hi[(size_t)row * H_ + hc] = hib;
                hw_lo[(size_t)row * H_ + hc] = f2b(hnew - b2f(hib));
            }
        }

        __syncthreads();   // drains vmcnt: all h stores of this block are L2-visible
        if (t < S_ - 1) {
            if (fast && tid == 0)
                __hip_atomic_store(&flag[g * 32 + hs], (unsigned int)(t + 1),
                                   __ATOMIC_RELAXED, __HIP_MEMORY_SCOPE_AGENT);
            xgemm(dir ? (S_ - 2 - t) : (t + 1));   // overlap next x-part with wait
        }
    }
}

// ---------------- attention scores: wave per (s,b) row ----------------------------
__global__ __launch_bounds__(256) void scores_kernel(const u16* h_hi, const float* attn_w,
                                                     const float* attn_b, float* scores)
{
    int wid = threadIdx.x >> 6, l = threadIdx.x & 63;
    int row = blockIdx.x * 4 + wid;          // row = s*256+b
    int dir = l >> 5;
    int hc = (l & 31) * 16;
    const u16* hp = h_hi + (size_t)dir * BS_ * H_ + (size_t)row * H_ + hc;
    s8_t v0 = *(const s8_t*)(hp);
    s8_t v1 = *(const s8_t*)(hp + 8);
    const float* aw = attn_w + dir * H_ + hc;
    float acc = 0.f;
#pragma unroll
    for (int j = 0; j < 8; ++j) acc += b2f((u16)v0[j]) * aw[j];
#pragma unroll
    for (int j = 0; j < 8; ++j) acc += b2f((u16)v1[j]) * aw[8 + j];
    for (int off = 32; off; off >>= 1) acc += __shfl_down(acc, off);
    if (l == 0) {
        int s = row >> 8, b = row & 255;
        scores[b * S_ + s] = acc + attn_b[0];
    }
}

// ---------------- softmax over S + weighted context -------------------------------
__global__ __launch_bounds__(256) void attnctx_kernel(const u16* h_hi, const float* scores,
                                                      float* ctx)
{
    __shared__ float sc[S_];
    __shared__ float tmp[S_];
    int b = blockIdx.x, tid = threadIdx.x;
    if (tid < S_) sc[tid] = scores[b * S_ + tid];
    __syncthreads();
    if (tid < S_) tmp[tid] = sc[tid];
    __syncthreads();
    for (int st = 64; st > 0; st >>= 1) {
        if (tid < st) tmp[tid] = fmaxf(tmp[tid], tmp[tid + st]);
        __syncthreads();
    }
    float mx = tmp[0];
    __syncthreads();
    if (tid < S_) { sc[tid] = __expf(sc[tid] - mx); tmp[tid] = sc[tid]; }
    __syncthreads();
    for (int st = 64; st > 0; st >>= 1) {
        if (tid < st) tmp[tid] += tmp[tid + st];
        __syncthreads();
    }
    float inv = 1.f / tmp[0];
    __syncthreads();
    if (tid < S_) sc[tid] *= inv;
    __syncthreads();

    int c = tid * 4;
    int dir = c >> 9, hcv = c & (H_ - 1);
    const u16* hp = h_hi + (size_t)dir * BS_ * H_;
    float a0 = 0, a1 = 0, a2 = 0, a3 = 0;
    for (int s = 0; s < S_; ++s) {
        float w = sc[s];
        s4v_t v = *(const s4v_t*)(hp + ((size_t)s * B_ + b) * H_ + hcv);
        a0 += w * b2f((u16)v[0]); a1 += w * b2f((u16)v[1]);
        a2 += w * b2f((u16)v[2]); a3 += w * b2f((u16)v[3]);
    }
    float* cp = ctx + (size_t)b * 1024 + c;
    cp[0] = a0; cp[1] = a1; cp[2] = a2; cp[3] = a3;
}

// ---------------- intent logits ---------------------------------------------------
__global__ __launch_bounds__(256) void intent_kernel(const float* ctx, const float* fc_w,
                                                     const float* fc_b, float* out)
{
    __shared__ float cs[1024];
    int b = blockIdx.x, tid = threadIdx.x;
    for (int i = tid; i < 1024; i += 256) cs[i] = ctx[(size_t)b * 1024 + i];
    __syncthreads();
    if (tid < O_) {
        float acc = fc_b[tid];
        const float* w = fc_w + (size_t)tid * 1024;
        for (int k = 0; k < 1024; ++k) acc += cs[k] * w[k];
        out[b * O_ + tid] = acc;
    }
}

// ---------------- emissions via MFMA: em[b][s][21] fp32 ---------------------------
__global__ __launch_bounds__(256) void emis_kernel(const u16* h_hi, const u16* nerw,
                                                   const float* ner_b, float* em)
{
    int tid = threadIdx.x, l = tid & 63, wid = tid >> 6;
    int rb = blockIdx.x * 64 + wid * 16;
    int lr = l & 15, lk = (l >> 4) * 8;
    f4_t acc[2] = {};
    for (int kk = 0; kk < 32; ++kk) {
        int k0 = kk * 32 + lk;
        int dir = k0 >> 9, hcv = k0 & (H_ - 1);
        s8_t a  = *(const s8_t*)(h_hi + (size_t)dir * BS_ * H_ + (size_t)(rb + lr) * H_ + hcv);
        s8_t b0 = *(const s8_t*)(nerw + (size_t)lr * 1024 + k0);
        s8_t b1 = *(const s8_t*)(nerw + (size_t)(16 + lr) * 1024 + k0);
        acc[0] = __builtin_amdgcn_mfma_f32_16x16x32_bf16(a, b0, acc[0], 0, 0, 0);
        acc[1] = __builtin_amdgcn_mfma_f32_16x16x32_bf16(a, b1, acc[1], 0, 0, 0);
    }
    int lc = l & 15, lr4 = (l >> 4) * 4;
#pragma unroll
    for (int f = 0; f < 2; ++f) {
        int tcol = f * 16 + lc;
        if (tcol < T_) {
            float nb = ner_b[tcol];
#pragma unroll
            for (int r = 0; r < 4; ++r) {
                int row = rb + lr4 + r;
                int s = row >> 8, bb = row & 255;
                em[((size_t)bb * S_ + s) * T_ + tcol] = acc[f][r] + nb;
            }
        }
    }
}

// ---------------- CRF numerator ---------------------------------------------------
__global__ void num_kernel(const int* tags, const float* em, const float* cstart,
                           const float* cend, const float* ctrans, float* numv)
{
    int b = blockIdx.x * blockDim.x + threadIdx.x;
    if (b >= B_) return;
    const int* tg = tags + b * S_;
    int prev = tg[0];
    float acc = cstart[prev] + em[((size_t)b * S_) * T_ + prev];
    for (int s = 1; s < S_; ++s) {
        int tc = tg[s];
        acc += em[((size_t)b * S_ + s) * T_ + tc] + ctrans[prev * T_ + tc];
        prev = tc;
    }
    acc += cend[prev];
    numv[b] = acc;
}

// ---------------- CRF forward (logZ): E=exp(trans) matvec form --------------------
__global__ __launch_bounds__(64) void crf2_kernel(const float* em, const float* cstart,
                                                  const float* cend, const float* ctrans,
                                                  float* logZ)
{
    int b = blockIdx.x, l = threadIdx.x;
    bool act = l < T_;
    float E[T_];
#pragma unroll
    for (int i = 0; i < T_; ++i) E[i] = act ? __expf(ctrans[i * T_ + l]) : 0.f;
    const float* eb = em + (size_t)b * S_ * T_;
    float sc = act ? (cstart[l] + eb[l]) : -1e30f;
#pragma unroll 1
    for (int s = 1; s < S_; ++s) {
        float emv = act ? eb[s * T_ + l] : 0.f;
        float m = sc;
#pragma unroll
        for (int off = 16; off; off >>= 1) m = fmaxf(m, __shfl_xor(m, off, 32));
        float e = act ? __expf(sc - m) : 0.f;
        float sum = 0.f;
#pragma unroll
        for (int i = 0; i < T_; ++i) sum += __shfl(e, i, 32) * E[i];
        sc = act ? (m + __logf(sum) + emv) : -1e30f;
    }
    float fin = act ? (sc + cend[l]) : -1e30f;
    float m = fin;
#pragma unroll
    for (int off = 16; off; off >>= 1) m = fmaxf(m, __shfl_xor(m, off, 32));
    float z = act ? __expf(fin - m) : 0.f;
#pragma unroll
    for (int off = 16; off; off >>= 1) z += __shfl_xor(z, off, 32);
    if (l == 0) logZ[b] = m + __logf(z);
}

// ---------------- final loss ------------------------------------------------------
__global__ __launch_bounds__(256) void loss_kernel(const float* numv, const float* logZ,
                                                   float* out)
{
    __shared__ float red[B_];
    int t = threadIdx.x;
    red[t] = numv[t] - logZ[t];
    __syncthreads();
    for (int st = 128; st > 0; st >>= 1) {
        if (t < st) red[t] += red[t + st];
        __syncthreads();
    }
    if (t == 0) out[16384] = -red[0] / (float)B_;
}

extern "C" void kernel_launch(void* const* d_in, const int* in_sizes, int n_in,
                              void* d_out, int out_size, void* d_ws, size_t ws_size,
                              hipStream_t stream)
{
    const int*   x      = (const int*)  d_in[0];
    const int*   tags   = (const int*)  d_in[1];
    const float* emb    = (const float*)d_in[3];
    const float* wih_f  = (const float*)d_in[4];
    const float* whh_f  = (const float*)d_in[5];
    const float* bih_f  = (const float*)d_in[6];
    const float* bhh_f  = (const float*)d_in[7];
    const float* wih_b  = (const float*)d_in[8];
    const float* whh_b  = (const float*)d_in[9];
    const float* bih_b  = (const float*)d_in[10];
    const float* bhh_b  = (const float*)d_in[11];
    const float* attn_w = (const float*)d_in[12];
    const float* attn_b = (const float*)d_in[13];
    const float* fc_w   = (const float*)d_in[14];
    const float* fc_b   = (const float*)d_in[15];
    const float* ner_w  = (const float*)d_in[16];
    const float* ner_b  = (const float*)d_in[17];
    const float* cstart = (const float*)d_in[18];
    const float* cend   = (const float*)d_in[19];
    const float* ctrans = (const float*)d_in[20];
    float* out = (float*)d_out;

    char* p = (char*)d_ws;
    auto alloc = [&](size_t bytes) { void* r = (void*)p; p += (bytes + 255) & ~(size_t)255; return r; };
    u16* wih_bf  = (u16*)alloc((size_t)3072 * EP_ * 2);
    u16* whh_hi  = (u16*)alloc((size_t)2 * G_ * H_ * 2);
    u16* whh_lo  = (u16*)alloc((size_t)2 * G_ * H_ * 2);
    u16* nerw_bf = (u16*)alloc((size_t)32 * 1024 * 2);
    u16* xe      = (u16*)alloc((size_t)BS_ * EP_ * 2);
    u16* h_hi    = (u16*)alloc((size_t)2 * BS_ * H_ * 2);
    u16* h_lo_pp = (u16*)alloc((size_t)4 * B_ * H_ * 2);
    unsigned int* flag = (unsigned int*)alloc(8 * 32 * 4);
    unsigned int* xcnt = (unsigned int*)alloc(64);
    float* scores= (float*)alloc((size_t)BS_ * 4);
    float* ctx   = (float*)alloc((size_t)B_ * 1024 * 4);
    float* em    = (float*)alloc((size_t)B_ * S_ * T_ * 4);
    float* numv  = (float*)alloc(1024);
    float* logZ  = (float*)alloc(1024);

    hipMemsetAsync(flag, 0, 8 * 32 * 4, stream);
    hipMemsetAsync(xcnt, 0, 64, stream);

    hipLaunchKernelGGL(prep_kernel, dim3(2048), dim3(256), 0, stream,
                       wih_f, wih_b, whh_f, whh_b, ner_w, wih_bf, whh_hi, whh_lo, nerw_bf);
    hipLaunchKernelGGL(gather_kernel, dim3(4096), dim3(256), 0, stream, x, emb, xe);

    void* args[] = { &xe, &wih_bf, &bih_f, &bih_b, &whh_hi, &whh_lo, &bhh_f, &bhh_b,
                     &h_hi, &h_lo_pp, &flag, &xcnt };
    hipLaunchCooperativeKernel((const void*)gru_persist, dim3(256), dim3(128), args, 0, stream);

    hipLaunchKernelGGL(scores_kernel, dim3(BS_ / 4), dim3(256), 0, stream,
                       h_hi, attn_w, attn_b, scores);
    hipLaunchKernelGGL(attnctx_kernel, dim3(B_), dim3(256), 0, stream, h_hi, scores, ctx);
    hipLaunchKernelGGL(intent_kernel, dim3(B_), dim3(256), 0, stream, ctx, fc_w, fc_b, out);
    hipLaunchKernelGGL(emis_kernel, dim3(BS_ / 64), dim3(256), 0, stream, h_hi, nerw_bf, ner_b, em);
    hipLaunchKernelGGL(num_kernel, dim3(1), dim3(256), 0, stream, tags, em, cstart, cend, ctrans, numv);
    hipLaunchKernelGGL(crf2_kernel, dim3(B_), dim3(64), 0, stream, em, cstart, cend, ctrans, logZ);
    hipLaunchKernelGGL(loss_kernel, dim3(1), dim3(256), 0, stream, numv, logZ, out);
}

// Round 6
// 1055.513 us; speedup vs baseline: 1.4004x; 1.4004x over previous
//
#include <hip/hip_runtime.h>
#include <hip/hip_cooperative_groups.h>
#include <stdint.h>

namespace cg = cooperative_groups;

typedef __attribute__((ext_vector_type(8))) short s8_t;    // 8 x bf16 (as short bits)
typedef __attribute__((ext_vector_type(4))) short s4v_t;   // 4 x bf16
typedef __attribute__((ext_vector_type(4))) float f4_t;    // MFMA accumulator
typedef unsigned short u16;

#define V_  50000
#define E_  300
#define EP_ 320
#define H_  512
#define G_  1536
#define O_  64
#define T_  21
#define B_  256
#define S_  128
#define BS_ 32768

__device__ __forceinline__ float b2f(u16 u) {
    union { unsigned int u; float f; } v; v.u = ((unsigned int)u) << 16; return v.f;
}
__device__ __forceinline__ u16 f2b(float f) {
    union { float f; unsigned int u; } v; v.f = f;
    unsigned int r = v.u + 0x7fffu + ((v.u >> 16) & 1u);
    return (u16)(r >> 16);
}
__device__ __forceinline__ float fsig(float x) {
    return __builtin_amdgcn_rcpf(1.f + __expf(-x));
}
__device__ __forceinline__ float ftanh(float x) {
    return 1.f - 2.f * __builtin_amdgcn_rcpf(1.f + __expf(2.f * x));
}

// ---------------- weight prep: fp32 -> bf16 ----------------------------------------
__global__ void prep_kernel(const float* wih_f, const float* wih_b,
                            const float* whh_f, const float* whh_b,
                            const float* ner_w,
                            u16* wih_bf, u16* whh_bf, u16* nerw_bf)
{
    const int NW = 3072 * EP_;
    const int NH = 2 * G_ * H_;
    const int NN = 32 * 1024;
    int stride = gridDim.x * blockDim.x;
    for (int i = blockIdx.x * blockDim.x + threadIdx.x; i < NW + NH + NN; i += stride) {
        if (i < NW) {
            int n = i / EP_, k = i % EP_;
            float v = 0.f;
            if (k < E_) v = (n < G_) ? wih_f[n * E_ + k] : wih_b[(n - G_) * E_ + k];
            wih_bf[i] = f2b(v);
        } else if (i < NW + NH) {
            int j = i - NW;
            int d = j / (G_ * H_), r = j % (G_ * H_);
            whh_bf[j] = f2b(d == 0 ? whh_f[r] : whh_b[r]);
        } else {
            int j = i - NW - NH;
            int t = j / 1024, k = j % 1024;
            nerw_bf[j] = f2b(t < T_ ? ner_w[t * 1024 + k] : 0.f);
        }
    }
}

// ---------------- embedding gather -> xe bf16 [s*B+b][EP_] (K padded w/ zeros) ----
__global__ void gather_kernel(const int* x, const float* emb, u16* xe)
{
    int stride = gridDim.x * blockDim.x;
    for (int i = blockIdx.x * blockDim.x + threadIdx.x; i < BS_ * EP_; i += stride) {
        int m = i / EP_, k = i % EP_;
        int s = m >> 8, b = m & 255;
        float v = 0.f;
        if (k < E_) v = emb[(size_t)x[b * S_ + s] * E_ + k];
        xe[i] = f2b(v);
    }
}

// ---------------- persistent BiGRU, XCD-local groups ------------------------------
// 256 blocks (1/CU), 4 waves x 16 rows. W_hh in bf16 (fp32 carry in regs gives
// ~1e-2 final error vs 7.8 loss threshold). W slice in LDS (~81 KB). Flag barrier:
// leader stores flag[g][hs]; wave0 lanes 0-31 poll all 32 flags coalesced. All
// cross-step h addresses are write-once/read-once-fresh -> no L1 invalidate needed.
// x-GEMM(t+1) overlaps the barrier wait. Fallback if placement != 32/XCD: grid.sync.
#define WST 520   // u16 stride for whh LDS rows
#define XST 328   // u16 stride for wih LDS rows
__global__ __launch_bounds__(256, 1) void gru_persist(
    const u16* __restrict__ xe, const u16* __restrict__ wih,
    const float* bih_f, const float* bih_b,
    const u16* __restrict__ whh_bf,
    const float* bhh_f, const float* bhh_b,
    u16* h_hi, unsigned int* flag, unsigned int* xcnt)
{
    __shared__ u16 sWhh[48 * WST];
    __shared__ u16 sWx [48 * XST];
    __shared__ unsigned int role_sh[2];

    cg::grid_group grid = cg::this_grid();
    int tid = threadIdx.x, l = tid & 63, wid = tid >> 6;   // wid 0..3

    if (tid == 0) {
        unsigned int xcc = __builtin_amdgcn_s_getreg((7u << 11) | 20u) & 7u;
        unsigned int slot = __hip_atomic_fetch_add(&xcnt[xcc], 1u,
                                __ATOMIC_RELAXED, __HIP_MEMORY_SCOPE_AGENT);
        role_sh[0] = xcc; role_sh[1] = slot;
    }
    grid.sync();
    bool fast = true;
    for (int i = 0; i < 8; ++i)
        fast = fast && (__hip_atomic_load(&xcnt[i], __ATOMIC_RELAXED,
                            __HIP_MEMORY_SCOPE_AGENT) == 32u);
    int g, hs;
    if (fast) { g = (int)role_sh[0]; hs = (int)role_sh[1]; }
    else      { g = blockIdx.x >> 5; hs = blockIdx.x & 31; }
    int dir = g >> 2, bt = g & 3;
    int r0  = bt * 64 + wid * 16;
    int hc0 = hs * 16;

    // ---- stage W slice into LDS (once) ----
    for (int idx = tid; idx < 48 * 64; idx += 256) {
        int rr = idx >> 6, ck = (idx & 63) * 8;
        int gcol = (rr >> 4) * H_ + hc0 + (rr & 15);
        size_t goff = ((size_t)dir * G_ + gcol) * (size_t)H_ + ck;
        *(s8_t*)&sWhh[rr * WST + ck] = *(const s8_t*)&whh_bf[goff];
    }
    for (int idx = tid; idx < 48 * 40; idx += 256) {
        int rr = idx / 40, ck = (idx % 40) * 8;
        int gcol = (rr >> 4) * H_ + hc0 + (rr & 15);
        size_t goff = ((size_t)dir * G_ + gcol) * (size_t)EP_ + ck;
        *(s8_t*)&sWx[rr * XST + ck] = *(const s8_t*)&wih[goff];
    }
    __syncthreads();

    int lr = l & 15, lk = (l >> 4) * 8;
    int lc = l & 15, lr4 = (l >> 4) * 4;
    int hc = hc0 + lc;
    const float* bih = dir ? bih_b : bih_f;
    const float* bhh = dir ? bhh_b : bhh_f;
    float br  = bih[hc] + bhh[hc];
    float bz  = bih[H_ + hc] + bhh[H_ + hc];
    float bxn = bih[2 * H_ + hc];
    float bhn = bhh[2 * H_ + hc];
    float hstate[4] = {0.f, 0.f, 0.f, 0.f};

    f4_t xac[3];                          // r, z, xn accumulators (x-part carried in)
    auto xgemm = [&](int ttx) {
#pragma unroll
        for (int c = 0; c < 3; ++c) xac[c] = (f4_t){0.f, 0.f, 0.f, 0.f};
        const u16* xp = xe + ((size_t)ttx * B_ + r0 + lr) * EP_ + lk;
#pragma unroll
        for (int kk = 0; kk < 10; ++kk) {
            s8_t ax = *(const s8_t*)(xp + kk * 32);
#pragma unroll
            for (int c = 0; c < 3; ++c) {
                s8_t bx = *(const s8_t*)&sWx[(c * 16 + lr) * XST + lk + kk * 32];
                xac[c] = __builtin_amdgcn_mfma_f32_16x16x32_bf16(ax, bx, xac[c], 0, 0, 0);
            }
        }
    };

    xgemm(dir ? (S_ - 1) : 0);            // prologue: x-part for t=0

#pragma unroll 1
    for (int t = 0; t < S_; ++t) {
        int tt = dir ? (S_ - 1 - t) : t;

        if (t > 0) {
            unsigned int tgt = (unsigned int)t;
            if (fast) {
                if (tid < 64) {
                    int slot = l & 31;
                    while (__hip_atomic_load(&flag[g * 32 + slot], __ATOMIC_RELAXED,
                                             __HIP_MEMORY_SCOPE_AGENT) < tgt)
                        __builtin_amdgcn_s_sleep(1);
                }
                __syncthreads();
                // no L1 invalidate needed: every h_hi line read below is fresh
                // (write-once by a same-XCD block, never before touched by this CU)
            } else {
                __threadfence();
                grid.sync();
                __threadfence();
            }
        }

        f4_t ahn = {0.f, 0.f, 0.f, 0.f};  // recurrent n-gate part (kept separate)
        if (t > 0) {
            int prev = dir ? (tt + 1) : (tt - 1);
            const u16* hb = h_hi + ((size_t)dir * S_ + prev) * B_ * H_
                                 + (size_t)(r0 + lr) * H_ + lk;
#pragma unroll
            for (int kk = 0; kk < 16; ++kk) {
                s8_t ah = *(const s8_t*)(hb + kk * 32);
#pragma unroll
                for (int c = 0; c < 3; ++c) {
                    s8_t bh = *(const s8_t*)&sWhh[(c * 16 + lr) * WST + lk + kk * 32];
                    if (c < 2)
                        xac[c] = __builtin_amdgcn_mfma_f32_16x16x32_bf16(ah, bh, xac[c], 0, 0, 0);
                    else
                        ahn = __builtin_amdgcn_mfma_f32_16x16x32_bf16(ah, bh, ahn, 0, 0, 0);
                }
            }
        }

        u16* hw = h_hi + ((size_t)dir * S_ + tt) * B_ * H_;
#pragma unroll
        for (int r = 0; r < 4; ++r) {
            int row = r0 + lr4 + r;
            float pre_r = xac[0][r] + br;
            float pre_z = xac[1][r] + bz;
            float xn = xac[2][r] + bxn;
            float hnv = ahn[r] + bhn;
            float rg = fsig(pre_r);
            float zg = fsig(pre_z);
            float ng = ftanh(xn + rg * hnv);
            float hnew = (1.f - zg) * ng + zg * hstate[r];
            hstate[r] = hnew;
            hw[(size_t)row * H_ + hc] = f2b(hnew);
        }

        __syncthreads();   // drains vmcnt: all h stores of this block are L2-visible
        if (t < S_ - 1) {
            if (fast && tid == 0)
                __hip_atomic_store(&flag[g * 32 + hs], (unsigned int)(t + 1),
                                   __ATOMIC_RELAXED, __HIP_MEMORY_SCOPE_AGENT);
            xgemm(dir ? (S_ - 2 - t) : (t + 1));   // overlap next x-part with wait
        }
    }
}

// ---------------- attention scores: wave per (s,b) row ----------------------------
__global__ __launch_bounds__(256) void scores_kernel(const u16* h_hi, const float* attn_w,
                                                     const float* attn_b, float* scores)
{
    int wid = threadIdx.x >> 6, l = threadIdx.x & 63;
    int row = blockIdx.x * 4 + wid;          // row = s*256+b
    int dir = l >> 5;
    int hc = (l & 31) * 16;
    const u16* hp = h_hi + (size_t)dir * BS_ * H_ + (size_t)row * H_ + hc;
    s8_t v0 = *(const s8_t*)(hp);
    s8_t v1 = *(const s8_t*)(hp + 8);
    const float* aw = attn_w + dir * H_ + hc;
    float acc = 0.f;
#pragma unroll
    for (int j = 0; j < 8; ++j) acc += b2f((u16)v0[j]) * aw[j];
#pragma unroll
    for (int j = 0; j < 8; ++j) acc += b2f((u16)v1[j]) * aw[8 + j];
    for (int off = 32; off; off >>= 1) acc += __shfl_down(acc, off);
    if (l == 0) {
        int s = row >> 8, b = row & 255;
        scores[b * S_ + s] = acc + attn_b[0];
    }
}

// ---------------- softmax over S + weighted context -------------------------------
__global__ __launch_bounds__(256) void attnctx_kernel(const u16* h_hi, const float* scores,
                                                      float* ctx)
{
    __shared__ float sc[S_];
    __shared__ float tmp[S_];
    int b = blockIdx.x, tid = threadIdx.x;
    if (tid < S_) sc[tid] = scores[b * S_ + tid];
    __syncthreads();
    if (tid < S_) tmp[tid] = sc[tid];
    __syncthreads();
    for (int st = 64; st > 0; st >>= 1) {
        if (tid < st) tmp[tid] = fmaxf(tmp[tid], tmp[tid + st]);
        __syncthreads();
    }
    float mx = tmp[0];
    __syncthreads();
    if (tid < S_) { sc[tid] = __expf(sc[tid] - mx); tmp[tid] = sc[tid]; }
    __syncthreads();
    for (int st = 64; st > 0; st >>= 1) {
        if (tid < st) tmp[tid] += tmp[tid + st];
        __syncthreads();
    }
    float inv = 1.f / tmp[0];
    __syncthreads();
    if (tid < S_) sc[tid] *= inv;
    __syncthreads();

    int c = tid * 4;
    int dir = c >> 9, hcv = c & (H_ - 1);
    const u16* hp = h_hi + (size_t)dir * BS_ * H_;
    float a0 = 0, a1 = 0, a2 = 0, a3 = 0;
    for (int s = 0; s < S_; ++s) {
        float w = sc[s];
        s4v_t v = *(const s4v_t*)(hp + ((size_t)s * B_ + b) * H_ + hcv);
        a0 += w * b2f((u16)v[0]); a1 += w * b2f((u16)v[1]);
        a2 += w * b2f((u16)v[2]); a3 += w * b2f((u16)v[3]);
    }
    float* cp = ctx + (size_t)b * 1024 + c;
    cp[0] = a0; cp[1] = a1; cp[2] = a2; cp[3] = a3;
}

// ---------------- intent logits ---------------------------------------------------
__global__ __launch_bounds__(256) void intent_kernel(const float* ctx, const float* fc_w,
                                                     const float* fc_b, float* out)
{
    __shared__ float cs[1024];
    int b = blockIdx.x, tid = threadIdx.x;
    for (int i = tid; i < 1024; i += 256) cs[i] = ctx[(size_t)b * 1024 + i];
    __syncthreads();
    if (tid < O_) {
        float acc = fc_b[tid];
        const float* w = fc_w + (size_t)tid * 1024;
        for (int k = 0; k < 1024; ++k) acc += cs[k] * w[k];
        out[b * O_ + tid] = acc;
    }
}

// ---------------- emissions via MFMA: em[b][s][21] fp32 ---------------------------
__global__ __launch_bounds__(256) void emis_kernel(const u16* h_hi, const u16* nerw,
                                                   const float* ner_b, float* em)
{
    int tid = threadIdx.x, l = tid & 63, wid = tid >> 6;
    int rb = blockIdx.x * 64 + wid * 16;
    int lr = l & 15, lk = (l >> 4) * 8;
    f4_t acc[2] = {};
    for (int kk = 0; kk < 32; ++kk) {
        int k0 = kk * 32 + lk;
        int dir = k0 >> 9, hcv = k0 & (H_ - 1);
        s8_t a  = *(const s8_t*)(h_hi + (size_t)dir * BS_ * H_ + (size_t)(rb + lr) * H_ + hcv);
        s8_t b0 = *(const s8_t*)(nerw + (size_t)lr * 1024 + k0);
        s8_t b1 = *(const s8_t*)(nerw + (size_t)(16 + lr) * 1024 + k0);
        acc[0] = __builtin_amdgcn_mfma_f32_16x16x32_bf16(a, b0, acc[0], 0, 0, 0);
        acc[1] = __builtin_amdgcn_mfma_f32_16x16x32_bf16(a, b1, acc[1], 0, 0, 0);
    }
    int lc = l & 15, lr4 = (l >> 4) * 4;
#pragma unroll
    for (int f = 0; f < 2; ++f) {
        int tcol = f * 16 + lc;
        if (tcol < T_) {
            float nb = ner_b[tcol];
#pragma unroll
            for (int r = 0; r < 4; ++r) {
                int row = rb + lr4 + r;
                int s = row >> 8, bb = row & 255;
                em[((size_t)bb * S_ + s) * T_ + tcol] = acc[f][r] + nb;
            }
        }
    }
}

// ---------------- CRF numerator ---------------------------------------------------
__global__ void num_kernel(const int* tags, const float* em, const float* cstart,
                           const float* cend, const float* ctrans, float* numv)
{
    int b = blockIdx.x * blockDim.x + threadIdx.x;
    if (b >= B_) return;
    const int* tg = tags + b * S_;
    int prev = tg[0];
    float acc = cstart[prev] + em[((size_t)b * S_) * T_ + prev];
    for (int s = 1; s < S_; ++s) {
        int tc = tg[s];
        acc += em[((size_t)b * S_ + s) * T_ + tc] + ctrans[prev * T_ + tc];
        prev = tc;
    }
    acc += cend[prev];
    numv[b] = acc;
}

// ---------------- CRF forward (logZ): E=exp(trans) matvec form --------------------
__global__ __launch_bounds__(64) void crf2_kernel(const float* em, const float* cstart,
                                                  const float* cend, const float* ctrans,
                                                  float* logZ)
{
    int b = blockIdx.x, l = threadIdx.x;
    bool act = l < T_;
    float E[T_];
#pragma unroll
    for (int i = 0; i < T_; ++i) E[i] = act ? __expf(ctrans[i * T_ + l]) : 0.f;
    const float* eb = em + (size_t)b * S_ * T_;
    float sc = act ? (cstart[l] + eb[l]) : -1e30f;
#pragma unroll 1
    for (int s = 1; s < S_; ++s) {
        float emv = act ? eb[s * T_ + l] : 0.f;
        float m = sc;
#pragma unroll
        for (int off = 16; off; off >>= 1) m = fmaxf(m, __shfl_xor(m, off, 32));
        float e = act ? __expf(sc - m) : 0.f;
        float sum = 0.f;
#pragma unroll
        for (int i = 0; i < T_; ++i) sum += __shfl(e, i, 32) * E[i];
        sc = act ? (m + __logf(sum) + emv) : -1e30f;
    }
    float fin = act ? (sc + cend[l]) : -1e30f;
    float m = fin;
#pragma unroll
    for (int off = 16; off; off >>= 1) m = fmaxf(m, __shfl_xor(m, off, 32));
    float z = act ? __expf(fin - m) : 0.f;
#pragma unroll
    for (int off = 16; off; off >>= 1) z += __shfl_xor(z, off, 32);
    if (l == 0) logZ[b] = m + __logf(z);
}

// ---------------- final loss ------------------------------------------------------
__global__ __launch_bounds__(256) void loss_kernel(const float* numv, const float* logZ,
                                                   float* out)
{
    __shared__ float red[B_];
    int t = threadIdx.x;
    red[t] = numv[t] - logZ[t];
    __syncthreads();
    for (int st = 128; st > 0; st >>= 1) {
        if (t < st) red[t] += red[t + st];
        __syncthreads();
    }
    if (t == 0) out[16384] = -red[0] / (float)B_;
}

extern "C" void kernel_launch(void* const* d_in, const int* in_sizes, int n_in,
                              void* d_out, int out_size, void* d_ws, size_t ws_size,
                              hipStream_t stream)
{
    const int*   x      = (const int*)  d_in[0];
    const int*   tags   = (const int*)  d_in[1];
    const float* emb    = (const float*)d_in[3];
    const float* wih_f  = (const float*)d_in[4];
    const float* whh_f  = (const float*)d_in[5];
    const float* bih_f  = (const float*)d_in[6];
    const float* bhh_f  = (const float*)d_in[7];
    const float* wih_b  = (const float*)d_in[8];
    const float* whh_b  = (const float*)d_in[9];
    const float* bih_b  = (const float*)d_in[10];
    const float* bhh_b  = (const float*)d_in[11];
    const float* attn_w = (const float*)d_in[12];
    const float* attn_b = (const float*)d_in[13];
    const float* fc_w   = (const float*)d_in[14];
    const float* fc_b   = (const float*)d_in[15];
    const float* ner_w  = (const float*)d_in[16];
    const float* ner_b  = (const float*)d_in[17];
    const float* cstart = (const float*)d_in[18];
    const float* cend   = (const float*)d_in[19];
    const float* ctrans = (const float*)d_in[20];
    float* out = (float*)d_out;

    char* p = (char*)d_ws;
    auto alloc = [&](size_t bytes) { void* r = (void*)p; p += (bytes + 255) & ~(size_t)255; return r; };
    u16* wih_bf  = (u16*)alloc((size_t)3072 * EP_ * 2);
    u16* whh_bf  = (u16*)alloc((size_t)2 * G_ * H_ * 2);
    u16* nerw_bf = (u16*)alloc((size_t)32 * 1024 * 2);
    u16* xe      = (u16*)alloc((size_t)BS_ * EP_ * 2);
    u16* h_hi    = (u16*)alloc((size_t)2 * BS_ * H_ * 2);
    unsigned int* flag = (unsigned int*)alloc(8 * 32 * 4);
    unsigned int* xcnt = (unsigned int*)alloc(64);
    float* scores= (float*)alloc((size_t)BS_ * 4);
    float* ctx   = (float*)alloc((size_t)B_ * 1024 * 4);
    float* em    = (float*)alloc((size_t)B_ * S_ * T_ * 4);
    float* numv  = (float*)alloc(1024);
    float* logZ  = (float*)alloc(1024);

    hipMemsetAsync(flag, 0, 8 * 32 * 4, stream);
    hipMemsetAsync(xcnt, 0, 64, stream);

    hipLaunchKernelGGL(prep_kernel, dim3(2048), dim3(256), 0, stream,
                       wih_f, wih_b, whh_f, whh_b, ner_w, wih_bf, whh_bf, nerw_bf);
    hipLaunchKernelGGL(gather_kernel, dim3(4096), dim3(256), 0, stream, x, emb, xe);

    void* args[] = { &xe, &wih_bf, &bih_f, &bih_b, &whh_bf, &bhh_f, &bhh_b,
                     &h_hi, &flag, &xcnt };
    hipLaunchCooperativeKernel((const void*)gru_persist, dim3(256), dim3(256), args, 0, stream);

    hipLaunchKernelGGL(scores_kernel, dim3(BS_ / 4), dim3(256), 0, stream,
                       h_hi, attn_w, attn_b, scores);
    hipLaunchKernelGGL(attnctx_kernel, dim3(B_), dim3(256), 0, stream, h_hi, scores, ctx);
    hipLaunchKernelGGL(intent_kernel, dim3(B_), dim3(256), 0, stream, ctx, fc_w, fc_b, out);
    hipLaunchKernelGGL(emis_kernel, dim3(BS_ / 64), dim3(256), 0, stream, h_hi, nerw_bf, ner_b, em);
    hipLaunchKernelGGL(num_kernel, dim3(1), dim3(256), 0, stream, tags, em, cstart, cend, ctrans, numv);
    hipLaunchKernelGGL(crf2_kernel, dim3(B_), dim3(64), 0, stream, em, cstart, cend, ctrans, logZ);
    hipLaunchKernelGGL(loss_kernel, dim3(1), dim3(256), 0, stream, numv, logZ, out);
}